// Round 5
// baseline (107.941 us; speedup 1.0000x reference)
//
#include <hip/hip_runtime.h>

// Levenshtein(seq1[1:], seq2[1:]) — bit-parallel Myers, 2047-bit column in
// 64 lanes x u32, lane-skewed systolic schedule (lane w does column j at
// t=j+w; cross-word carry/shift bits via v_mov_b32_dpp wave_shr:1).
// Hirschberg split: fwd chain over B[0:1024] and bwd chain over reversed
// B[1024:2047] run INTERLEAVED IN ONE WAVE — two independent dependency
// chains fill each other's VALU latency gaps (single-wave SIMD is
// latency-bound, ~5-6 cy/instr serialized otherwise).

#define PLEN 2047
#define HF   1024
#define HB   1023
#define TPAD 64
#define TXTB 1232            // TPAD + max col index 1103 + slack
#define TSTEPS 1088          // multiple of 8; covers max nsave 1086
#define TSPLIT 1016          // multiple of 8, <= min nsave (1022)

__device__ __forceinline__ unsigned dpp_shr1(unsigned x) {
    // wave_shr:1 (0x138): lane w receives lane w-1; lane 0 receives 0.
    return (unsigned)__builtin_amdgcn_update_dpp(0, (int)x, 0x138, 0xF, 0xF, true);
}

// One Myers column step for one chain; NCO/NPH/NMH = neighbor's prev words.
#define MSTEP(EQ, PV, MV, NCO, NPH, NMH, SP, SM, DOSAVE, TT, NSV)          \
  do {                                                                     \
    unsigned cin  = NCO >> 31;                                             \
    unsigned phin = (NPH >> 31) | L0;                                      \
    unsigned mhin = NMH >> 31;                                             \
    unsigned Xv = (EQ) | MV;                                               \
    unsigned Aa = (EQ) & PV;                                               \
    unsigned s  = Aa + PV + cin;                                           \
    unsigned co = Aa | (PV & ~s);     /* carry-out: g|p&~s, g=Aa⊆Pv=p */   \
    unsigned Xh = (s ^ PV) | (EQ);                                         \
    unsigned Ph = MV | ~(Xh | PV);                                         \
    unsigned Mh = PV & Xh;                                                 \
    NCO = dpp_shr1(co); NPH = dpp_shr1(Ph); NMH = dpp_shr1(Mh);            \
    unsigned PhS = (Ph << 1) | phin;                                       \
    unsigned MhS = (Mh << 1) | mhin;                                       \
    PV = MhS | ~(Xv | PhS);                                                \
    MV = PhS & Xv;                                                         \
    if (DOSAVE) {                                                          \
      SP = ((TT) == (NSV)) ? PV : SP;                                      \
      SM = ((TT) == (NSV)) ? MV : SM;                                      \
    }                                                                      \
  } while (0)

__global__ __launch_bounds__(128, 1)
void lev_v5(const float* __restrict__ s1, const float* __restrict__ s2,
            float* __restrict__ out) {
    __shared__ unsigned peqF[65 * 64];   // [char][word]; row 64 = zeros (pad)
    __shared__ unsigned peqB[65 * 64];
    __shared__ unsigned char tF8[TXTB];
    __shared__ unsigned char tB8[TXTB];
    __shared__ int Df[2048];
    __shared__ int Db[2048];

    const int tid  = threadIdx.x;
    const int lane = tid & 63;
    const int wave = tid >> 6;

    // ---- setup (both waves help) ----
    for (int k = tid; k < 65 * 64; k += 128) { peqF[k] = 0u; peqB[k] = 0u; }
    for (int j = tid; j < TXTB; j += 128) {
        int jj = j - TPAD;
        tF8[j] = (unsigned char)((jj >= 0 && jj < HF) ? (int)s2[1 + jj] : 64);
        tB8[j] = (unsigned char)((jj >= 0 && jj < HB) ? (int)s2[2047 - jj] : 64);
    }
    __syncthreads();
    if (wave == 0) {
        for (int b = 0; b < 32; ++b) {
            int i = 32 * lane + b;
            if (i < PLEN) peqF[((int)s1[1 + i]) * 64 + lane] |= (1u << b);
        }
    } else {
        for (int b = 0; b < 32; ++b) {
            int i = 32 * lane + b;
            if (i < PLEN) peqB[((int)s1[2047 - i]) * 64 + lane] |= (1u << b);
        }
    }
    __syncthreads();

    if (wave == 0) {
        const unsigned* peqFL = peqF + lane;
        const unsigned* peqBL = peqB + lane;
        const unsigned char* tF = tF8 + TPAD;
        const unsigned char* tB = tB8 + TPAD;
        const int nsaveA = HF - 1 + lane;      // fwd chain snapshot step
        const int nsaveB = HB - 1 + lane;      // bwd chain snapshot step

        unsigned PvA = (lane == 63) ? 0x7FFFFFFFu : 0xFFFFFFFFu, MvA = 0u;
        unsigned PvB = PvA, MvB = 0u;
        unsigned sPA = PvA, sMA = 0u, sPB = PvB, sMB = 0u;
        const unsigned L0 = (lane == 0) ? 1u : 0u;
        unsigned ncoA = 0u, nphA = 0u, nmhA = 0u;
        unsigned ncoB = 0u, nphB = 0u, nmhB = 0u;

        // ---- pipeline prologue: Eq for cols 0..7, chars for cols 8..15 ----
        unsigned eA0 = peqFL[tF[0 - lane] * 64], eB0 = peqBL[tB[0 - lane] * 64];
        unsigned eA1 = peqFL[tF[1 - lane] * 64], eB1 = peqBL[tB[1 - lane] * 64];
        unsigned eA2 = peqFL[tF[2 - lane] * 64], eB2 = peqBL[tB[2 - lane] * 64];
        unsigned eA3 = peqFL[tF[3 - lane] * 64], eB3 = peqBL[tB[3 - lane] * 64];
        unsigned eA4 = peqFL[tF[4 - lane] * 64], eB4 = peqBL[tB[4 - lane] * 64];
        unsigned eA5 = peqFL[tF[5 - lane] * 64], eB5 = peqBL[tB[5 - lane] * 64];
        unsigned eA6 = peqFL[tF[6 - lane] * 64], eB6 = peqBL[tB[6 - lane] * 64];
        unsigned eA7 = peqFL[tF[7 - lane] * 64], eB7 = peqBL[tB[7 - lane] * 64];
        unsigned cA0 = tF[ 8 - lane], cB0 = tB[ 8 - lane];
        unsigned cA1 = tF[ 9 - lane], cB1 = tB[ 9 - lane];
        unsigned cA2 = tF[10 - lane], cB2 = tB[10 - lane];
        unsigned cA3 = tF[11 - lane], cB3 = tB[11 - lane];
        unsigned cA4 = tF[12 - lane], cB4 = tB[12 - lane];
        unsigned cA5 = tF[13 - lane], cB5 = tB[13 - lane];
        unsigned cA6 = tF[14 - lane], cB6 = tB[14 - lane];
        unsigned cA7 = tF[15 - lane], cB7 = tB[15 - lane];

        // ---- main region: no save checks ----
        for (int t0 = 0; t0 < TSPLIT; t0 += 8) {
            MSTEP(eA0, PvA, MvA, ncoA, nphA, nmhA, sPA, sMA, 0, 0, 0); eA0 = peqFL[cA0 * 64]; cA0 = tF[t0 + 16 - lane];
            MSTEP(eB0, PvB, MvB, ncoB, nphB, nmhB, sPB, sMB, 0, 0, 0); eB0 = peqBL[cB0 * 64]; cB0 = tB[t0 + 16 - lane];
            MSTEP(eA1, PvA, MvA, ncoA, nphA, nmhA, sPA, sMA, 0, 0, 0); eA1 = peqFL[cA1 * 64]; cA1 = tF[t0 + 17 - lane];
            MSTEP(eB1, PvB, MvB, ncoB, nphB, nmhB, sPB, sMB, 0, 0, 0); eB1 = peqBL[cB1 * 64]; cB1 = tB[t0 + 17 - lane];
            MSTEP(eA2, PvA, MvA, ncoA, nphA, nmhA, sPA, sMA, 0, 0, 0); eA2 = peqFL[cA2 * 64]; cA2 = tF[t0 + 18 - lane];
            MSTEP(eB2, PvB, MvB, ncoB, nphB, nmhB, sPB, sMB, 0, 0, 0); eB2 = peqBL[cB2 * 64]; cB2 = tB[t0 + 18 - lane];
            MSTEP(eA3, PvA, MvA, ncoA, nphA, nmhA, sPA, sMA, 0, 0, 0); eA3 = peqFL[cA3 * 64]; cA3 = tF[t0 + 19 - lane];
            MSTEP(eB3, PvB, MvB, ncoB, nphB, nmhB, sPB, sMB, 0, 0, 0); eB3 = peqBL[cB3 * 64]; cB3 = tB[t0 + 19 - lane];
            MSTEP(eA4, PvA, MvA, ncoA, nphA, nmhA, sPA, sMA, 0, 0, 0); eA4 = peqFL[cA4 * 64]; cA4 = tF[t0 + 20 - lane];
            MSTEP(eB4, PvB, MvB, ncoB, nphB, nmhB, sPB, sMB, 0, 0, 0); eB4 = peqBL[cB4 * 64]; cB4 = tB[t0 + 20 - lane];
            MSTEP(eA5, PvA, MvA, ncoA, nphA, nmhA, sPA, sMA, 0, 0, 0); eA5 = peqFL[cA5 * 64]; cA5 = tF[t0 + 21 - lane];
            MSTEP(eB5, PvB, MvB, ncoB, nphB, nmhB, sPB, sMB, 0, 0, 0); eB5 = peqBL[cB5 * 64]; cB5 = tB[t0 + 21 - lane];
            MSTEP(eA6, PvA, MvA, ncoA, nphA, nmhA, sPA, sMA, 0, 0, 0); eA6 = peqFL[cA6 * 64]; cA6 = tF[t0 + 22 - lane];
            MSTEP(eB6, PvB, MvB, ncoB, nphB, nmhB, sPB, sMB, 0, 0, 0); eB6 = peqBL[cB6 * 64]; cB6 = tB[t0 + 22 - lane];
            MSTEP(eA7, PvA, MvA, ncoA, nphA, nmhA, sPA, sMA, 0, 0, 0); eA7 = peqFL[cA7 * 64]; cA7 = tF[t0 + 23 - lane];
            MSTEP(eB7, PvB, MvB, ncoB, nphB, nmhB, sPB, sMB, 0, 0, 0); eB7 = peqBL[cB7 * 64]; cB7 = tB[t0 + 23 - lane];
        }
        // ---- tail region: snapshot state at t == nsave ----
        for (int t0 = TSPLIT; t0 < TSTEPS; t0 += 8) {
            MSTEP(eA0, PvA, MvA, ncoA, nphA, nmhA, sPA, sMA, 1, t0 + 0, nsaveA); eA0 = peqFL[cA0 * 64]; cA0 = tF[t0 + 16 - lane];
            MSTEP(eB0, PvB, MvB, ncoB, nphB, nmhB, sPB, sMB, 1, t0 + 0, nsaveB); eB0 = peqBL[cB0 * 64]; cB0 = tB[t0 + 16 - lane];
            MSTEP(eA1, PvA, MvA, ncoA, nphA, nmhA, sPA, sMA, 1, t0 + 1, nsaveA); eA1 = peqFL[cA1 * 64]; cA1 = tF[t0 + 17 - lane];
            MSTEP(eB1, PvB, MvB, ncoB, nphB, nmhB, sPB, sMB, 1, t0 + 1, nsaveB); eB1 = peqBL[cB1 * 64]; cB1 = tB[t0 + 17 - lane];
            MSTEP(eA2, PvA, MvA, ncoA, nphA, nmhA, sPA, sMA, 1, t0 + 2, nsaveA); eA2 = peqFL[cA2 * 64]; cA2 = tF[t0 + 18 - lane];
            MSTEP(eB2, PvB, MvB, ncoB, nphB, nmhB, sPB, sMB, 1, t0 + 2, nsaveB); eB2 = peqBL[cB2 * 64]; cB2 = tB[t0 + 18 - lane];
            MSTEP(eA3, PvA, MvA, ncoA, nphA, nmhA, sPA, sMA, 1, t0 + 3, nsaveA); eA3 = peqFL[cA3 * 64]; cA3 = tF[t0 + 19 - lane];
            MSTEP(eB3, PvB, MvB, ncoB, nphB, nmhB, sPB, sMB, 1, t0 + 3, nsaveB); eB3 = peqBL[cB3 * 64]; cB3 = tB[t0 + 19 - lane];
            MSTEP(eA4, PvA, MvA, ncoA, nphA, nmhA, sPA, sMA, 1, t0 + 4, nsaveA); eA4 = peqFL[cA4 * 64]; cA4 = tF[t0 + 20 - lane];
            MSTEP(eB4, PvB, MvB, ncoB, nphB, nmhB, sPB, sMB, 1, t0 + 4, nsaveB); eB4 = peqBL[cB4 * 64]; cB4 = tB[t0 + 20 - lane];
            MSTEP(eA5, PvA, MvA, ncoA, nphA, nmhA, sPA, sMA, 1, t0 + 5, nsaveA); eA5 = peqFL[cA5 * 64]; cA5 = tF[t0 + 21 - lane];
            MSTEP(eB5, PvB, MvB, ncoB, nphB, nmhB, sPB, sMB, 1, t0 + 5, nsaveB); eB5 = peqBL[cB5 * 64]; cB5 = tB[t0 + 21 - lane];
            MSTEP(eA6, PvA, MvA, ncoA, nphA, nmhA, sPA, sMA, 1, t0 + 6, nsaveA); eA6 = peqFL[cA6 * 64]; cA6 = tF[t0 + 22 - lane];
            MSTEP(eB6, PvB, MvB, ncoB, nphB, nmhB, sPB, sMB, 1, t0 + 6, nsaveB); eB6 = peqBL[cB6 * 64]; cB6 = tB[t0 + 22 - lane];
            MSTEP(eA7, PvA, MvA, ncoA, nphA, nmhA, sPA, sMA, 1, t0 + 7, nsaveA); eA7 = peqFL[cA7 * 64]; cA7 = tF[t0 + 23 - lane];
            MSTEP(eB7, PvB, MvB, ncoB, nphB, nmhB, sPB, sMB, 1, t0 + 7, nsaveB); eB7 = peqBL[cB7 * 64]; cB7 = tB[t0 + 23 - lane];
        }

        // ---- boundary distances: shfl prefix-scan of word deltas, expand ----
        {
            int dA = __popc(sPA) - __popc(sMA);
            int dB = __popc(sPB) - __popc(sMB);
            int scA = dA, scB = dB;
            #pragma unroll
            for (int mm = 1; mm < 64; mm <<= 1) {
                int tA = __shfl_up(scA, mm, 64);
                int tB_ = __shfl_up(scB, mm, 64);
                scA += (lane >= mm) ? tA : 0;
                scB += (lane >= mm) ? tB_ : 0;
            }
            int vA = HF + scA - dA;      // exclusive prefix + D[0]=ncols
            int vB = HB + scB - dB;
            for (int b = 0; b < 32; ++b) {
                Df[32 * lane + b] = vA;
                Db[32 * lane + b] = vB;
                vA += (int)((sPA >> b) & 1u) - (int)((sMA >> b) & 1u);
                vB += (int)((sPB >> b) & 1u) - (int)((sMB >> b) & 1u);
            }
        }
    }
    __syncthreads();

    // ---- Hirschberg combine: min_i Df[i] + Db[2047-i] ----
    if (wave == 0) {
        int best = 0x7fffffff;
        for (int b = 0; b < 32; ++b) {
            int i = 32 * lane + b;
            int cand = Df[i] + Db[2047 - i];
            best = (cand < best) ? cand : best;
        }
        for (int mm = 32; mm; mm >>= 1) {
            int o = __shfl_xor(best, mm, 64);
            best = (o < best) ? o : best;
        }
        if (lane == 0) out[0] = (float)best;
    }
}

extern "C" void kernel_launch(void* const* d_in, const int* in_sizes, int n_in,
                              void* d_out, int out_size, void* d_ws, size_t ws_size,
                              hipStream_t stream) {
    const float* s1 = (const float*)d_in[0];
    const float* s2 = (const float*)d_in[1];
    float* out = (float*)d_out;
    lev_v5<<<dim3(1), dim3(128), 0, stream>>>(s1, s2, out);
}

// Round 6
// 64.382 us; speedup vs baseline: 1.6766x; 1.6766x over previous
//
#include <hip/hip_runtime.h>

// Levenshtein(seq1[1:], seq2[1:]) — bit-parallel Myers, 2047-bit column in
// 64 lanes x u32, lane-skewed systolic schedule (lane w does column j at
// t=j+w). Two waves: wave0 = forward chain over B[0:1024], wave1 = backward
// chain over reversed B[1024:2047] (Hirschberg). Inner loop is hand-written
// inline asm: 21 VALU/step, DPP wave_shr:1 carries (bound_ctrl-preserve
// seeds lane0's phin=1 for free), v_alignbit fuses the shift-in bits.
// LDS loads double-buffered in C between asm blocks (no rotation movs).

#define PLEN 2047
#define HF   1024
#define HB   1023
#define TPAD 64
#define TXTB 1232            // TPAD + max col index 1103 + slack
#define TSTEPS 1088          // multiple of 16; covers max nsave 1086
#define TSPLIT 1008          // multiple of 16, <= min nsave (1022); tail 80

// One Myers step, hand-scheduled. EQ is the asm operand name of this step's
// Eq word. Cross-word bits arrive in nco/nph/nmh (neighbor's previous step,
// via DPP). alignbit(X, nold, 31) = (X<<1)|(nold>>31) = shifted word with
// neighbor bit. DPP sources are >=3 instrs old (2-wait-state hazard).
#define MS(EQ) \
  "v_lshrrev_b32 %[cin], 31, %[nco]\n"                                    \
  "v_and_b32 %[aa], " EQ ", %[pv]\n"                                      \
  "v_or_b32 %[xv], " EQ ", %[mv]\n"                                       \
  "v_add3_u32 %[s], %[aa], %[pv], %[cin]\n"                               \
  "v_not_b32 %[ns], %[s]\n"                                               \
  "v_xor_b32 %[xh], %[s], %[pv]\n"                                        \
  "v_and_or_b32 %[co], %[pv], %[ns], %[aa]\n"                             \
  "v_or_b32 %[xh], %[xh], " EQ "\n"                                       \
  "v_or_b32 %[tp], %[xh], %[pv]\n"                                        \
  "v_and_b32 %[mh], %[pv], %[xh]\n"                                       \
  "v_not_b32 %[tp], %[tp]\n"                                              \
  "v_mov_b32_dpp %[nco], %[co] wave_shr:1 row_mask:0xf bank_mask:0xf\n"   \
  "v_or_b32 %[ph], %[tp], %[mv]\n"                                        \
  "v_alignbit_b32 %[mhs], %[mh], %[nmh], 31\n"                            \
  "v_mov_b32_dpp %[nmh], %[mh] wave_shr:1 row_mask:0xf bank_mask:0xf\n"   \
  "v_alignbit_b32 %[phs], %[ph], %[nph], 31\n"                            \
  "v_mov_b32_dpp %[nph], %[ph] wave_shr:1 row_mask:0xf bank_mask:0xf\n"   \
  "v_or_b32 %[to], %[xv], %[phs]\n"                                       \
  "v_and_b32 %[mv], %[phs], %[xv]\n"                                      \
  "v_not_b32 %[to], %[to]\n"                                              \
  "v_or_b32 %[pv], %[to], %[mhs]\n"

// Snapshot Pv/Mv into sp/sm when (step-within-block K) == td.
#define MSV(K) \
  "v_cmp_eq_u32 vcc, " K ", %[td]\n"                                      \
  "v_cndmask_b32 %[sp], %[sp], %[pv], vcc\n"                              \
  "v_cndmask_b32 %[sm], %[sm], %[mv], vcc\n"

#define ASM8(A0,A1,A2,A3,A4,A5,A6,A7)                                     \
  asm volatile(                                                           \
    MS("%[q0]") MS("%[q1]") MS("%[q2]") MS("%[q3]")                       \
    MS("%[q4]") MS("%[q5]") MS("%[q6]") MS("%[q7]")                       \
    : [pv]"+v"(Pv), [mv]"+v"(Mv), [nco]"+v"(nco), [nph]"+v"(nph),         \
      [nmh]"+v"(nmh),                                                     \
      [cin]"=&v"(z0), [aa]"=&v"(z1), [xv]"=&v"(z2), [s]"=&v"(z3),         \
      [ns]"=&v"(z4), [xh]"=&v"(z5), [co]"=&v"(z6), [tp]"=&v"(z7),         \
      [mh]"=&v"(z8), [ph]"=&v"(z9), [mhs]"=&v"(z10), [phs]"=&v"(z11),     \
      [to]"=&v"(z12)                                                      \
    : [q0]"v"(A0), [q1]"v"(A1), [q2]"v"(A2), [q3]"v"(A3),                 \
      [q4]"v"(A4), [q5]"v"(A5), [q6]"v"(A6), [q7]"v"(A7))

#define ASM8S(A0,A1,A2,A3,A4,A5,A6,A7,TD)                                 \
  asm volatile(                                                           \
    MS("%[q0]") MSV("0") MS("%[q1]") MSV("1")                             \
    MS("%[q2]") MSV("2") MS("%[q3]") MSV("3")                             \
    MS("%[q4]") MSV("4") MS("%[q5]") MSV("5")                             \
    MS("%[q6]") MSV("6") MS("%[q7]") MSV("7")                             \
    : [pv]"+v"(Pv), [mv]"+v"(Mv), [nco]"+v"(nco), [nph]"+v"(nph),         \
      [nmh]"+v"(nmh), [sp]"+v"(sP), [sm]"+v"(sM),                         \
      [cin]"=&v"(z0), [aa]"=&v"(z1), [xv]"=&v"(z2), [s]"=&v"(z3),         \
      [ns]"=&v"(z4), [xh]"=&v"(z5), [co]"=&v"(z6), [tp]"=&v"(z7),         \
      [mh]"=&v"(z8), [ph]"=&v"(z9), [mhs]"=&v"(z10), [phs]"=&v"(z11),     \
      [to]"=&v"(z12)                                                      \
    : [q0]"v"(A0), [q1]"v"(A1), [q2]"v"(A2), [q3]"v"(A3),                 \
      [q4]"v"(A4), [q5]"v"(A5), [q6]"v"(A6), [q7]"v"(A7), [td]"v"(TD)     \
    : "vcc")

__global__ __launch_bounds__(128, 1)
void lev_v6(const float* __restrict__ s1, const float* __restrict__ s2,
            float* __restrict__ out) {
    __shared__ unsigned peqF[65 * 64];   // [char][word]; row 64 = zeros (pad)
    __shared__ unsigned peqB[65 * 64];
    __shared__ unsigned char tF8[TXTB];
    __shared__ unsigned char tB8[TXTB];
    __shared__ int Df[2048];
    __shared__ int Db[2048];

    const int tid  = threadIdx.x;
    const int lane = tid & 63;
    const int wave = tid >> 6;

    // ---- setup (both waves help) ----
    for (int k = tid; k < 65 * 64; k += 128) { peqF[k] = 0u; peqB[k] = 0u; }
    for (int j = tid; j < TXTB; j += 128) {
        int jj = j - TPAD;
        tF8[j] = (unsigned char)((jj >= 0 && jj < HF) ? (int)s2[1 + jj] : 64);
        tB8[j] = (unsigned char)((jj >= 0 && jj < HB) ? (int)s2[2047 - jj] : 64);
    }
    __syncthreads();
    if (wave == 0) {
        for (int b = 0; b < 32; ++b) {
            int i = 32 * lane + b;
            if (i < PLEN) peqF[((int)s1[1 + i]) * 64 + lane] |= (1u << b);
        }
    } else {
        for (int b = 0; b < 32; ++b) {
            int i = 32 * lane + b;
            if (i < PLEN) peqB[((int)s1[2047 - i]) * 64 + lane] |= (1u << b);
        }
    }
    __syncthreads();

    const unsigned* peqL = (wave ? peqB : peqF) + lane;
    const unsigned char* txt = (wave ? tB8 : tF8) + TPAD;
    const int ncols = wave ? HB : HF;
    const int nsave = ncols - 1 + lane;

    unsigned Pv = (lane == 63) ? 0x7FFFFFFFu : 0xFFFFFFFFu;
    unsigned Mv = 0u;
    unsigned sP = Pv, sM = 0u;
    unsigned nco = 0u, nmh = 0u;
    unsigned nph = (lane == 0) ? 0x80000000u : 0u;   // lane0 phin=1 forever
    unsigned z0, z1, z2, z3, z4, z5, z6, z7, z8, z9, z10, z11, z12;

    // ---- pipeline prologue: Eq for cols 0..7, chars for cols 8..15 ----
    unsigned e0 = peqL[txt[0 - lane] * 64];
    unsigned e1 = peqL[txt[1 - lane] * 64];
    unsigned e2 = peqL[txt[2 - lane] * 64];
    unsigned e3 = peqL[txt[3 - lane] * 64];
    unsigned e4 = peqL[txt[4 - lane] * 64];
    unsigned e5 = peqL[txt[5 - lane] * 64];
    unsigned e6 = peqL[txt[6 - lane] * 64];
    unsigned e7 = peqL[txt[7 - lane] * 64];
    unsigned c0 = txt[ 8 - lane], c1 = txt[ 9 - lane];
    unsigned c2 = txt[10 - lane], c3 = txt[11 - lane];
    unsigned c4 = txt[12 - lane], c5 = txt[13 - lane];
    unsigned c6 = txt[14 - lane], c7 = txt[15 - lane];
    unsigned f0, f1, f2, f3, f4, f5, f6, f7;
    unsigned d0, d1, d2, d3, d4, d5, d6, d7;

    // ---- main region: 16 steps/iteration, no save checks ----
    for (int t0 = 0; t0 < TSPLIT; t0 += 16) {
        f0 = peqL[c0 * 64]; f1 = peqL[c1 * 64];
        f2 = peqL[c2 * 64]; f3 = peqL[c3 * 64];
        f4 = peqL[c4 * 64]; f5 = peqL[c5 * 64];
        f6 = peqL[c6 * 64]; f7 = peqL[c7 * 64];
        d0 = txt[t0 + 16 - lane]; d1 = txt[t0 + 17 - lane];
        d2 = txt[t0 + 18 - lane]; d3 = txt[t0 + 19 - lane];
        d4 = txt[t0 + 20 - lane]; d5 = txt[t0 + 21 - lane];
        d6 = txt[t0 + 22 - lane]; d7 = txt[t0 + 23 - lane];
        ASM8(e0, e1, e2, e3, e4, e5, e6, e7);
        e0 = peqL[d0 * 64]; e1 = peqL[d1 * 64];
        e2 = peqL[d2 * 64]; e3 = peqL[d3 * 64];
        e4 = peqL[d4 * 64]; e5 = peqL[d5 * 64];
        e6 = peqL[d6 * 64]; e7 = peqL[d7 * 64];
        c0 = txt[t0 + 24 - lane]; c1 = txt[t0 + 25 - lane];
        c2 = txt[t0 + 26 - lane]; c3 = txt[t0 + 27 - lane];
        c4 = txt[t0 + 28 - lane]; c5 = txt[t0 + 29 - lane];
        c6 = txt[t0 + 30 - lane]; c7 = txt[t0 + 31 - lane];
        ASM8(f0, f1, f2, f3, f4, f5, f6, f7);
    }
    // ---- tail region: snapshot state at t == nsave ----
    for (int t0 = TSPLIT; t0 < TSTEPS; t0 += 16) {
        int tdA = nsave - t0;
        int tdB = nsave - t0 - 8;
        f0 = peqL[c0 * 64]; f1 = peqL[c1 * 64];
        f2 = peqL[c2 * 64]; f3 = peqL[c3 * 64];
        f4 = peqL[c4 * 64]; f5 = peqL[c5 * 64];
        f6 = peqL[c6 * 64]; f7 = peqL[c7 * 64];
        d0 = txt[t0 + 16 - lane]; d1 = txt[t0 + 17 - lane];
        d2 = txt[t0 + 18 - lane]; d3 = txt[t0 + 19 - lane];
        d4 = txt[t0 + 20 - lane]; d5 = txt[t0 + 21 - lane];
        d6 = txt[t0 + 22 - lane]; d7 = txt[t0 + 23 - lane];
        ASM8S(e0, e1, e2, e3, e4, e5, e6, e7, tdA);
        e0 = peqL[d0 * 64]; e1 = peqL[d1 * 64];
        e2 = peqL[d2 * 64]; e3 = peqL[d3 * 64];
        e4 = peqL[d4 * 64]; e5 = peqL[d5 * 64];
        e6 = peqL[d6 * 64]; e7 = peqL[d7 * 64];
        c0 = txt[t0 + 24 - lane]; c1 = txt[t0 + 25 - lane];
        c2 = txt[t0 + 26 - lane]; c3 = txt[t0 + 27 - lane];
        c4 = txt[t0 + 28 - lane]; c5 = txt[t0 + 29 - lane];
        c6 = txt[t0 + 30 - lane]; c7 = txt[t0 + 31 - lane];
        ASM8S(f0, f1, f2, f3, f4, f5, f6, f7, tdB);
    }

    // ---- boundary distances: shfl prefix-scan of word deltas, expand ----
    {
        int delta = __popc(sP) - __popc(sM);
        int scan = delta;
        #pragma unroll
        for (int mm = 1; mm < 64; mm <<= 1) {
            int t = __shfl_up(scan, mm, 64);
            scan += (lane >= mm) ? t : 0;
        }
        int v = ncols + scan - delta;        // exclusive prefix + D[0]=ncols
        int* D = wave ? Db : Df;
        for (int b = 0; b < 32; ++b) {
            D[32 * lane + b] = v;
            v += (int)((sP >> b) & 1u) - (int)((sM >> b) & 1u);
        }
    }
    __syncthreads();

    // ---- Hirschberg combine: min_i Df[i] + Db[2047-i] ----
    if (wave == 0) {
        int best = 0x7fffffff;
        for (int b = 0; b < 32; ++b) {
            int i = 32 * lane + b;
            int cand = Df[i] + Db[2047 - i];
            best = (cand < best) ? cand : best;
        }
        for (int mm = 32; mm; mm >>= 1) {
            int o = __shfl_xor(best, mm, 64);
            best = (o < best) ? o : best;
        }
        if (lane == 0) out[0] = (float)best;
    }
}

extern "C" void kernel_launch(void* const* d_in, const int* in_sizes, int n_in,
                              void* d_out, int out_size, void* d_ws, size_t ws_size,
                              hipStream_t stream) {
    const float* s1 = (const float*)d_in[0];
    const float* s2 = (const float*)d_in[1];
    float* out = (float*)d_out;
    lev_v6<<<dim3(1), dim3(128), 0, stream>>>(s1, s2, out);
}

// Round 8
// 61.362 us; speedup vs baseline: 1.7591x; 1.0492x over previous
//
#include <hip/hip_runtime.h>

// Levenshtein(seq1[1:], seq2[1:]) — bit-parallel Myers, 2047-bit column in
// 64 lanes x u32, lane-skewed systolic schedule (lane w does column j at
// t=j+w). Two waves: wave0 = fwd chain over B[0:1024], wave1 = bwd chain
// over reversed B[1024:2047] (Hirschberg). Cross-word transport = v4's
// verified 3x v_mov_b32_dpp wave_shr:1 (nph preserve-seeded 0x80000000 on
// lane0 => phin=1 free). New: v_bfi_b32 fusions cut the step to 18 VALU:
//   co  = bfi(S, Aa, Pv)      ( = Aa | (Pv&~S), since Aa ⊆ Pv )
//   Ph  = bfi(T, Mv, -1)      ( = Mv | ~T )
//   Pv' = bfi(U, MhS, -1)     ( = MhS | ~U )
// cin is derived at the END of the producing step (dpp(co)>>31), off the
// next step's critical path. All asm is single-instruction VGPR-only.

#define PLEN 2047
#define HF   1024
#define HB   1023
#define TPAD 64
#define TXTB 1232            // TPAD + max col index 1103 + slack
#define TSTEPS 1088          // multiple of 8; covers max nsave 1086
#define TSPLIT 1016          // multiple of 8, <= min nsave (1022)

// One Myers column step. State: Pv, Mv, nph, nmh (VGPR), cin (VGPR 0/1).
#define MSTEP(EQ)                                                          \
  do {                                                                     \
    unsigned Xv = (EQ) | Mv;                                               \
    unsigned Aa = (EQ) & Pv;                                               \
    unsigned S  = Aa + Pv + cin;                       /* v_add3_u32 */    \
    unsigned co;                                                           \
    asm("v_bfi_b32 %0, %1, %2, %3"                                         \
        : "=v"(co) : "v"(S), "v"(Aa), "v"(Pv));                            \
    unsigned Xh = (S ^ Pv) | (EQ);                                         \
    unsigned T  = Xh | Pv;                                                 \
    unsigned Ph;                                                           \
    asm("v_bfi_b32 %0, %1, %2, -1" : "=v"(Ph) : "v"(T), "v"(Mv));          \
    unsigned Mh = Pv & Xh;                                                 \
    unsigned PhS = __builtin_amdgcn_alignbit(Ph, nph, 31);                 \
    unsigned MhS = __builtin_amdgcn_alignbit(Mh, nmh, 31);                 \
    nph = (unsigned)__builtin_amdgcn_update_dpp(                           \
        (int)nph, (int)Ph, 0x138, 0xF, 0xF, false);                        \
    nmh = (unsigned)__builtin_amdgcn_update_dpp(                           \
        (int)nmh, (int)Mh, 0x138, 0xF, 0xF, false);                        \
    cin = ((unsigned)__builtin_amdgcn_update_dpp(                          \
        0, (int)co, 0x138, 0xF, 0xF, true)) >> 31;                         \
    unsigned U = Xv | PhS;                                                 \
    asm("v_bfi_b32 %0, %1, %2, -1" : "=v"(Pv) : "v"(U), "v"(MhS));         \
    Mv = PhS & Xv;                                                         \
  } while (0)

__global__ __launch_bounds__(128, 1)
void lev_v8(const float* __restrict__ s1, const float* __restrict__ s2,
            float* __restrict__ out) {
    __shared__ unsigned peqF[65 * 64];   // [char][word]; row 64 = zeros (pad)
    __shared__ unsigned peqB[65 * 64];
    __shared__ unsigned char tF8[TXTB];
    __shared__ unsigned char tB8[TXTB];
    __shared__ int Df[2048];
    __shared__ int Db[2048];

    const int tid  = threadIdx.x;
    const int lane = tid & 63;
    const int wave = tid >> 6;

    // ---- setup (both waves help) ----
    for (int k = tid; k < 65 * 64; k += 128) { peqF[k] = 0u; peqB[k] = 0u; }
    for (int j = tid; j < TXTB; j += 128) {
        int jj = j - TPAD;
        tF8[j] = (unsigned char)((jj >= 0 && jj < HF) ? (int)s2[1 + jj] : 64);
        tB8[j] = (unsigned char)((jj >= 0 && jj < HB) ? (int)s2[2047 - jj] : 64);
    }
    __syncthreads();
    if (wave == 0) {
        for (int b = 0; b < 32; ++b) {
            int i = 32 * lane + b;
            if (i < PLEN) peqF[((int)s1[1 + i]) * 64 + lane] |= (1u << b);
        }
    } else {
        for (int b = 0; b < 32; ++b) {
            int i = 32 * lane + b;
            if (i < PLEN) peqB[((int)s1[2047 - i]) * 64 + lane] |= (1u << b);
        }
    }
    __syncthreads();

    const unsigned* peqL = (wave ? peqB : peqF) + lane;
    const unsigned char* txt = (wave ? tB8 : tF8) + TPAD;
    const int ncols = wave ? HB : HF;
    const int nsave = ncols - 1 + lane;

    unsigned Pv = (lane == 63) ? 0x7FFFFFFFu : 0xFFFFFFFFu;
    unsigned Mv = 0u;
    unsigned sP = Pv, sM = 0u;
    unsigned nmh = 0u;
    unsigned nph = (lane == 0) ? 0x80000000u : 0u;   // lane0 phin=1 forever
    unsigned cin = 0u;

    // ---- pipeline prologue: Eq for cols 0..7, chars for cols 8..15 ----
    unsigned e0 = peqL[txt[0 - lane] * 64];
    unsigned e1 = peqL[txt[1 - lane] * 64];
    unsigned e2 = peqL[txt[2 - lane] * 64];
    unsigned e3 = peqL[txt[3 - lane] * 64];
    unsigned e4 = peqL[txt[4 - lane] * 64];
    unsigned e5 = peqL[txt[5 - lane] * 64];
    unsigned e6 = peqL[txt[6 - lane] * 64];
    unsigned e7 = peqL[txt[7 - lane] * 64];
    unsigned c_0 = txt[ 8 - lane], c_1 = txt[ 9 - lane];
    unsigned c_2 = txt[10 - lane], c_3 = txt[11 - lane];
    unsigned c_4 = txt[12 - lane], c_5 = txt[13 - lane];
    unsigned c_6 = txt[14 - lane], c_7 = txt[15 - lane];

    // ---- main region: no save checks ----
    for (int t0 = 0; t0 < TSPLIT; t0 += 8) {
        MSTEP(e0); e0 = peqL[c_0 * 64]; c_0 = txt[t0 + 16 - lane];
        MSTEP(e1); e1 = peqL[c_1 * 64]; c_1 = txt[t0 + 17 - lane];
        MSTEP(e2); e2 = peqL[c_2 * 64]; c_2 = txt[t0 + 18 - lane];
        MSTEP(e3); e3 = peqL[c_3 * 64]; c_3 = txt[t0 + 19 - lane];
        MSTEP(e4); e4 = peqL[c_4 * 64]; c_4 = txt[t0 + 20 - lane];
        MSTEP(e5); e5 = peqL[c_5 * 64]; c_5 = txt[t0 + 21 - lane];
        MSTEP(e6); e6 = peqL[c_6 * 64]; c_6 = txt[t0 + 22 - lane];
        MSTEP(e7); e7 = peqL[c_7 * 64]; c_7 = txt[t0 + 23 - lane];
    }
    // ---- tail region: snapshot state at t == nsave ----
    for (int t0 = TSPLIT; t0 < TSTEPS; t0 += 8) {
        MSTEP(e0); sP = (t0 + 0 == nsave) ? Pv : sP; sM = (t0 + 0 == nsave) ? Mv : sM;
        e0 = peqL[c_0 * 64]; c_0 = txt[t0 + 16 - lane];
        MSTEP(e1); sP = (t0 + 1 == nsave) ? Pv : sP; sM = (t0 + 1 == nsave) ? Mv : sM;
        e1 = peqL[c_1 * 64]; c_1 = txt[t0 + 17 - lane];
        MSTEP(e2); sP = (t0 + 2 == nsave) ? Pv : sP; sM = (t0 + 2 == nsave) ? Mv : sM;
        e2 = peqL[c_2 * 64]; c_2 = txt[t0 + 18 - lane];
        MSTEP(e3); sP = (t0 + 3 == nsave) ? Pv : sP; sM = (t0 + 3 == nsave) ? Mv : sM;
        e3 = peqL[c_3 * 64]; c_3 = txt[t0 + 19 - lane];
        MSTEP(e4); sP = (t0 + 4 == nsave) ? Pv : sP; sM = (t0 + 4 == nsave) ? Mv : sM;
        e4 = peqL[c_4 * 64]; c_4 = txt[t0 + 20 - lane];
        MSTEP(e5); sP = (t0 + 5 == nsave) ? Pv : sP; sM = (t0 + 5 == nsave) ? Mv : sM;
        e5 = peqL[c_5 * 64]; c_5 = txt[t0 + 21 - lane];
        MSTEP(e6); sP = (t0 + 6 == nsave) ? Pv : sP; sM = (t0 + 6 == nsave) ? Mv : sM;
        e6 = peqL[c_6 * 64]; c_6 = txt[t0 + 22 - lane];
        MSTEP(e7); sP = (t0 + 7 == nsave) ? Pv : sP; sM = (t0 + 7 == nsave) ? Mv : sM;
        e7 = peqL[c_7 * 64]; c_7 = txt[t0 + 23 - lane];
    }

    // ---- boundary distances: shfl prefix-scan of word deltas, expand ----
    {
        int delta = __popc(sP) - __popc(sM);
        int scan = delta;
        #pragma unroll
        for (int mm = 1; mm < 64; mm <<= 1) {
            int t = __shfl_up(scan, mm, 64);
            scan += (lane >= mm) ? t : 0;
        }
        int v = ncols + scan - delta;        // exclusive prefix + D[0]=ncols
        int* D = wave ? Db : Df;
        for (int b = 0; b < 32; ++b) {
            D[32 * lane + b] = v;
            v += (int)((sP >> b) & 1u) - (int)((sM >> b) & 1u);
        }
    }
    __syncthreads();

    // ---- Hirschberg combine: min_i Df[i] + Db[2047-i] ----
    if (wave == 0) {
        int best = 0x7fffffff;
        for (int b = 0; b < 32; ++b) {
            int i = 32 * lane + b;
            int cand = Df[i] + Db[2047 - i];
            best = (cand < best) ? cand : best;
        }
        for (int mm = 32; mm; mm >>= 1) {
            int o = __shfl_xor(best, mm, 64);
            best = (o < best) ? o : best;
        }
        if (lane == 0) out[0] = (float)best;
    }
}

extern "C" void kernel_launch(void* const* d_in, const int* in_sizes, int n_in,
                              void* d_out, int out_size, void* d_ws, size_t ws_size,
                              hipStream_t stream) {
    const float* s1 = (const float*)d_in[0];
    const float* s2 = (const float*)d_in[1];
    float* out = (float*)d_out;
    lev_v8<<<dim3(1), dim3(128), 0, stream>>>(s1, s2, out);
}